// Round 3
// baseline (13932.277 us; speedup 1.0000x reference)
//
#include <hip/hip_runtime.h>

typedef long long ll;

#define TPB 256

static inline dim3 gridFor(ll n){ return dim3((unsigned)((n + TPB - 1) / TPB)); }

// ---------------- zero fill ----------------
__global__ void k_zero(float* __restrict__ p, ll n){
  ll i = (ll)blockIdx.x*blockDim.x + threadIdx.x;
  if(i<n) p[i] = 0.f;
}
__global__ void k_copy(const float* __restrict__ in, float* __restrict__ out, ll n){
  ll i = (ll)blockIdx.x*blockDim.x + threadIdx.x;
  if(i<n) out[i] = in[i];
}

// ---------------- conv3d 3x3x3 SAME + relu (conv1) ----------------
__global__ void k_conv1(const float* __restrict__ x, const float* __restrict__ w,
                        float* __restrict__ out, int B,int Ci,int Co,int D,int H,int W)
{
  ll idx = (ll)blockIdx.x*blockDim.x + threadIdx.x;
  ll total = (ll)B*Co*D*H*W;
  if(idx>=total) return;
  int wv = (int)(idx % W); ll t = idx / W;
  int hv = (int)(t % H); t /= H;
  int dv = (int)(t % D); t /= D;
  int co = (int)(t % Co); int b = (int)(t / Co);
  ll plane = (ll)D*H*W;
  const float* xb = x + (ll)b*Ci*plane;
  const float* wc = w + (ll)co*Ci*27;
  float acc = 0.f;
  for(int ci=0; ci<Ci; ++ci){
    const float* xc = xb + (ll)ci*plane;
    const float* wk = wc + ci*27;
    for(int kd=0;kd<3;++kd){
      int dd = dv+kd-1; if((unsigned)dd >= (unsigned)D) continue;
      for(int kh=0;kh<3;++kh){
        int hh = hv+kh-1; if((unsigned)hh >= (unsigned)H) continue;
        const float* rowp = xc + ((ll)dd*H + hh)*W;
        const float* wrow = wk + (kd*3+kh)*3;
        for(int kw=0;kw<3;++kw){
          int ww = wv+kw-1; if((unsigned)ww >= (unsigned)W) continue;
          acc += rowp[ww]*wrow[kw];
        }
      }
    }
  }
  out[idx] = fmaxf(acc, 0.f);
}

// ---------------- fused conv2 + 1x1 skip + relu + maxpool(1,2,2) (stages 1,2) ----------------
__global__ void k_conv2respool(const float* __restrict__ cin, const float* __restrict__ xin,
                               const float* __restrict__ w2, const float* __restrict__ wsk,
                               float* __restrict__ out, int B,int Cm,int Co,int Cs,int D,int H,int W)
{
  int Ho = H/2, Wo = W/2;
  ll idx = (ll)blockIdx.x*blockDim.x + threadIdx.x;
  ll total = (ll)B*Co*D*Ho*Wo;
  if(idx>=total) return;
  int wo = (int)(idx % Wo); ll t = idx / Wo;
  int ho = (int)(t % Ho); t /= Ho;
  int dv = (int)(t % D); t /= D;
  int co = (int)(t % Co); int b = (int)(t / Co);
  ll plane = (ll)D*H*W;
  const float* cb = cin + (ll)b*Cm*plane;
  const float* xb = xin + (ll)b*Cs*plane;
  const float* wc = w2 + (ll)co*Cm*27;
  const float* wr = wsk + (ll)co*Cs;
  float m = -3.4e38f;
  for(int py=0; py<2; ++py){
    for(int px=0; px<2; ++px){
      int hv = 2*ho+py, wv = 2*wo+px;
      float acc = 0.f;
      ll sp = ((ll)dv*H + hv)*W + wv;
      for(int cs=0; cs<Cs; ++cs) acc += xb[(ll)cs*plane + sp]*wr[cs];
      for(int ci=0; ci<Cm; ++ci){
        const float* xc = cb + (ll)ci*plane;
        const float* wk = wc + ci*27;
        for(int kd=0;kd<3;++kd){
          int dd = dv+kd-1; if((unsigned)dd >= (unsigned)D) continue;
          for(int kh=0;kh<3;++kh){
            int hh = hv+kh-1; if((unsigned)hh >= (unsigned)H) continue;
            const float* rowp = xc + ((ll)dd*H + hh)*W;
            const float* wrow = wk + (kd*3+kh)*3;
            for(int kw=0;kw<3;++kw){
              int ww = wv+kw-1; if((unsigned)ww >= (unsigned)W) continue;
              acc += rowp[ww]*wrow[kw];
            }
          }
        }
      }
      m = fmaxf(m, fmaxf(acc, 0.f));
    }
  }
  out[idx] = m;
}

// ---------------- conv2 + (1x1 skip | identity) + relu (stages 3-6) ----------------
__global__ void k_conv2res(const float* __restrict__ cin, const float* __restrict__ xin,
                           const float* __restrict__ w2, const float* __restrict__ wsk,
                           float* __restrict__ out, int B,int Cm,int Co,int Cs,int D,int H,int W)
{
  ll idx = (ll)blockIdx.x*blockDim.x + threadIdx.x;
  ll total = (ll)B*Co*D*H*W;
  if(idx>=total) return;
  int wv = (int)(idx % W); ll t = idx / W;
  int hv = (int)(t % H); t /= H;
  int dv = (int)(t % D); t /= D;
  int co = (int)(t % Co); int b = (int)(t / Co);
  ll plane = (ll)D*H*W;
  ll sp = ((ll)dv*H + hv)*W + wv;
  float acc;
  if(wsk){
    acc = 0.f;
    const float* xs = xin + (ll)b*Cs*plane + sp;
    const float* wr = wsk + (ll)co*Cs;
    for(int cs=0; cs<Cs; ++cs) acc += xs[(ll)cs*plane]*wr[cs];
  } else {
    acc = xin[((ll)b*Co + co)*plane + sp];
  }
  const float* cb = cin + (ll)b*Cm*plane;
  const float* wc = w2 + (ll)co*Cm*27;
  for(int ci=0; ci<Cm; ++ci){
    const float* xc = cb + (ll)ci*plane;
    const float* wk = wc + ci*27;
    for(int kd=0;kd<3;++kd){
      int dd = dv+kd-1; if((unsigned)dd >= (unsigned)D) continue;
      for(int kh=0;kh<3;++kh){
        int hh = hv+kh-1; if((unsigned)hh >= (unsigned)H) continue;
        const float* rowp = xc + ((ll)dd*H + hh)*W;
        const float* wrow = wk + (kd*3+kh)*3;
        for(int kw=0;kw<3;++kw){
          int ww = wv+kw-1; if((unsigned)ww >= (unsigned)W) continue;
          acc += rowp[ww]*wrow[kw];
        }
      }
    }
  }
  out[idx] = fmaxf(acc, 0.f);
}

// ---------------- maxpool3d (window==stride) ----------------
__global__ void k_maxpool(const float* __restrict__ x, float* __restrict__ out,
                          int B,int C,int D,int H,int W,int pd,int ph,int pw)
{
  int Do = D/pd, Ho = H/ph, Wo = W/pw;
  ll total = (ll)B*C*Do*Ho*Wo;
  ll i = (ll)blockIdx.x*blockDim.x + threadIdx.x;
  if(i>=total) return;
  int w0 = (int)(i % Wo); ll t = i / Wo;
  int h0 = (int)(t % Ho); t /= Ho;
  int d0 = (int)(t % Do); t /= Do;
  int c  = (int)(t % C);  int b = (int)(t / C);
  const float* xb = x + ((ll)b*C + c)*D*H*W;
  float m = -3.4e38f;
  for(int dd=0; dd<pd; ++dd)
    for(int hh=0; hh<ph; ++hh)
      for(int ww=0; ww<pw; ++ww){
        float v = xb[(((ll)(d0*pd+dd))*H + (h0*ph+hh))*W + (w0*pw+ww)];
        m = fmaxf(m, v);
      }
  out[i] = m;
}

// ---------------- mu linear with block reduction ----------------
__global__ void k_linear_red(const float* __restrict__ x, const float* __restrict__ w,
                             const float* __restrict__ bias, float* __restrict__ out,
                             int In, int Out)
{
  int o = blockIdx.x % Out;
  int b = blockIdx.x / Out;
  const float* xr = x + (ll)b*In;
  const float* wr = w + (ll)o*In;
  float s = 0.f;
  for(int i = threadIdx.x; i < In; i += blockDim.x) s += xr[i]*wr[i];
  __shared__ float red[TPB];
  red[threadIdx.x] = s; __syncthreads();
  for(int off = TPB/2; off > 0; off >>= 1){
    if(threadIdx.x < off) red[threadIdx.x] += red[threadIdx.x + off];
    __syncthreads();
  }
  if(threadIdx.x == 0) out[blockIdx.x] = red[0] + bias[o];
}

// ---------------- latent->decoder linear + relu ----------------
__global__ void k_ld(const float* __restrict__ z, const float* __restrict__ w,
                     const float* __restrict__ bias, float* __restrict__ out,
                     int B,int Out,int L)
{
  ll i = (ll)blockIdx.x*blockDim.x + threadIdx.x;
  if(i >= (ll)B*Out) return;
  int o = (int)(i % Out); int b = (int)(i / Out);
  const float* zr = z + (ll)b*L;
  const float* wr = w + (ll)o*L;
  float s = bias[o];
  for(int l=0; l<L; ++l) s += zr[l]*wr[l];
  out[i] = fmaxf(s, 0.f);
}

// ---------------- cheb graph helpers ----------------
__global__ void k_deg(const int* __restrict__ row, float* __restrict__ deg, int E){
  int e = blockIdx.x*blockDim.x + threadIdx.x;
  if(e<E) atomicAdd(&deg[row[e]], 1.f);
}
__global__ void k_edgenorm(const int* __restrict__ row, const int* __restrict__ col,
                           const float* __restrict__ deg, float* __restrict__ nrm, int E){
  int e = blockIdx.x*blockDim.x + threadIdx.x;
  if(e>=E) return;
  float dr = deg[row[e]], dc = deg[col[e]];
  float ir = dr > 0.f ? rsqrtf(dr) : 0.f;
  float ic = dc > 0.f ? rsqrtf(dc) : 0.f;
  nrm[e] = -(ir*ic);
}
__global__ void k_scatter(const float* __restrict__ v, const float* __restrict__ nrm,
                          const int* __restrict__ row, const int* __restrict__ col,
                          float* __restrict__ out, int B,int N,int C,int E)
{
  ll i = (ll)blockIdx.x*blockDim.x + threadIdx.x;
  ll total = (ll)B*E*C;
  if(i>=total) return;
  int c = (int)(i % C); ll t = i / C;
  int e = (int)(t % E); int b = (int)(t / E);
  float m = v[((ll)b*N + row[e])*C + c]*nrm[e];
  atomicAdd(&out[((ll)b*N + col[e])*C + c], m);
}
__global__ void k_recur(float* __restrict__ t2, const float* __restrict__ t0, ll n){
  ll i = (ll)blockIdx.x*blockDim.x + threadIdx.x;
  if(i<n) t2[i] = 2.f*t2[i] - t0[i];
}
__global__ void k_nodemm(const float* __restrict__ x, const float* __restrict__ w,
                         float* __restrict__ out, ll BN, int C, int F, int add)
{
  ll i = (ll)blockIdx.x*blockDim.x + threadIdx.x;
  if(i >= BN*(ll)F) return;
  int f = (int)(i % F); ll r = i / F;
  const float* xr = x + r*(ll)C;
  float s = add ? out[i] : 0.f;
  for(int c=0; c<C; ++c) s += xr[c]*w[(ll)c*F + f];
  out[i] = s;
}
__global__ void k_inorm(float* __restrict__ x, const float* __restrict__ bias, ll BN, int C)
{
  ll r = (ll)blockIdx.x*blockDim.x + threadIdx.x;
  if(r>=BN) return;
  float* xr = x + r*(ll)C;
  float mu = 0.f;
  for(int c=0;c<C;++c){ float v = xr[c] + bias[c]; xr[c]=v; mu += v; }
  mu /= (float)C;
  float var = 0.f;
  for(int c=0;c<C;++c){ float d = xr[c]-mu; var += d*d; }
  var /= (float)C;
  float inv = rsqrtf(var + 1e-5f);
  for(int c=0;c<C;++c) xr[c] = fmaxf((xr[c]-mu)*inv, 0.f);
}

// ---------------- IGSC ----------------
__global__ void k_copycols(const float* __restrict__ x, float* __restrict__ cat,
                           ll BN, int Cx, int Ctot)
{
  ll i = (ll)blockIdx.x*blockDim.x + threadIdx.x;
  if(i >= BN*(ll)Cx) return;
  int c = (int)(i % Cx); ll r = i / Cx;
  cat[r*(ll)Ctot + c] = x[i];
}
// pos = x @ igw ; writes pos into cat tail and into ds output (f32)
__global__ void k_pos(const float* __restrict__ x, const float* __restrict__ igw,
                      float* __restrict__ cat, float* __restrict__ ds,
                      ll BN, int Cx, int Ctot, int posoff)
{
  ll i = (ll)blockIdx.x*blockDim.x + threadIdx.x;
  if(i>=BN) return;
  const float* xr = x + i*(ll)Cx;
  float p0=0.f,p1=0.f,p2=0.f;
  for(int c=0;c<Cx;++c){
    float v = xr[c];
    p0 += v*igw[c*3+0];
    p1 += v*igw[c*3+1];
    p2 += v*igw[c*3+2];
  }
  float* rowp = cat + i*(ll)Ctot + posoff;
  rowp[0]=p0; rowp[1]=p1; rowp[2]=p2;
  ds[i*3+0]=p0; ds[i*3+1]=p1; ds[i*3+2]=p2;
}
// trilinear grid sample (align_corners=True, zeros pad), grid = 2*pos-1
__global__ void k_gsample(const float* __restrict__ feat, float* __restrict__ cat,
                          int B,int N,int Cf,int D,int H,int W,int Ctot,int xoff,int posoff)
{
  ll i = (ll)blockIdx.x*blockDim.x + threadIdx.x;
  ll total = (ll)B*N*Cf;
  if(i>=total) return;
  int c = (int)(i % Cf); ll t = i / Cf;
  int n = (int)(t % N); int b = (int)(t / N);
  float* rowp = cat + ((ll)b*N + n)*Ctot;
  float px = rowp[posoff+0], py = rowp[posoff+1], pz = rowp[posoff+2];
  float gx = (2.f*px - 1.f + 1.f)*0.5f*(W-1);
  float gy = (2.f*py - 1.f + 1.f)*0.5f*(H-1);
  float gz = (2.f*pz - 1.f + 1.f)*0.5f*(D-1);
  float x0 = floorf(gx), y0 = floorf(gy), z0 = floorf(gz);
  const float* fb = feat + ((ll)b*Cf + c)*D*H*W;
  float acc = 0.f;
  for(int dz=0; dz<2; ++dz)
    for(int dy=0; dy<2; ++dy)
      for(int dx=0; dx<2; ++dx){
        float xi = x0+dx, yi = y0+dy, zi = z0+dz;
        float wgt = (1.f-fabsf(gx-xi))*(1.f-fabsf(gy-yi))*(1.f-fabsf(gz-zi));
        bool valid = (xi>=0.f)&&(xi<=(float)(W-1))&&(yi>=0.f)&&(yi<=(float)(H-1))&&(zi>=0.f)&&(zi<=(float)(D-1));
        int xc = min(max((int)xi,0),W-1);
        int yc = min(max((int)yi,0),H-1);
        int zc = min(max((int)zi,0),D-1);
        if(valid) acc += fb[((ll)zc*H + yc)*W + xc]*wgt;
      }
  rowp[xoff + c] = acc;
}

// ---------------- unpool ----------------
__global__ void k_unpool(const float* __restrict__ xin, const int* __restrict__ idx,
                         const float* __restrict__ w, float* __restrict__ out,
                         int B,int Ni,int No,int C)
{
  ll i = (ll)blockIdx.x*blockDim.x + threadIdx.x;
  ll total = (ll)B*No*C;
  if(i>=total) return;
  int c = (int)(i % C); ll t = i / C;
  int no = (int)(t % No); int b = (int)(t / No);
  float s = 0.f;
  for(int k=0;k<3;++k){
    s += xin[((ll)b*Ni + idx[no*3+k])*C + c]*w[no*3+k];
  }
  out[i] = s;
}

// ================= workspace layout (BYTE offsets, total ~126 MiB) =================
static const ll BO_A   = 0;            // f32 scratch, cap 18,874,368 fl (75,497,472 B); decoder arena
static const ll BO_B   = 75497472;     // f32, cap 4,718,592 fl (18,874,368 B)
static const ll BO_C   = 94371840;     // f32, cap 2,359,296 fl ( 9,437,184 B)
static const ll BO_L3  = 103809024;    // 4,718,592 fl
static const ll BO_L4  = 122683392;    // 1,179,648 fl
static const ll BO_L5  = 127401984;    //   589,824 fl
static const ll BO_L6  = 129761280;    //   294,912 fl
static const ll BO_P5  = 130940928;    //   294,912 fl
static const ll BO_Z   = 132120576;    // 256 fl -> end 132,121,600
// decoder f32 regions inside arena A [0, 75,497,472)
static const ll BO_DX   = 0;           // cap 2,948,000 fl
static const ll BO_DT1  = 11792000;    // cap 2,948,000 fl
static const ll BO_DT2  = 23584000;    // cap 2,948,000 fl
static const ll BO_DO   = 35376000;    // cap 1,408,000 fl
static const ll BO_DCAT = 41008000;    // cap 1,474,000 fl
static const ll BO_DNRM = 46904000;    // cap 66,000 fl
static const ll BO_DDEG = 47168000;    // cap 11,000 fl -> end 47,212,000

extern "C" void kernel_launch(void* const* d_in, const int* in_sizes, int n_in,
                              void* d_out, int out_size, void* d_ws, size_t ws_size,
                              hipStream_t stream)
{
  (void)in_sizes; (void)n_in; (void)out_size; (void)ws_size;
  const int B = 4;
  const float* sax = (const float*)d_in[0];
  const float *w1[7], *w2[7], *wsk[7];
  for(int i=1;i<=5;++i){
    w1[i]  = (const float*)d_in[1 + (i-1)*3];
    w2[i]  = (const float*)d_in[2 + (i-1)*3];
    wsk[i] = (const float*)d_in[3 + (i-1)*3];
  }
  w1[6] = (const float*)d_in[16]; w2[6] = (const float*)d_in[17]; wsk[6] = nullptr;
  const float* mu_w = (const float*)d_in[18];
  const float* mu_b = (const float*)d_in[19];
  const float* ld_w = (const float*)d_in[22];
  const float* ld_b = (const float*)d_in[23];
  const float *gcw[5], *gcb[5];
  for(int i=0;i<5;++i){ gcw[i] = (const float*)d_in[24+2*i]; gcb[i] = (const float*)d_in[25+2*i]; }
  const float* gcout_w = (const float*)d_in[34];
  const float* igw[4];
  for(int i=0;i<4;++i) igw[i] = (const float*)d_in[35+i];
  const int* edge[5];
  for(int i=0;i<5;++i) edge[i] = (const int*)d_in[39+i];
  const int* upidx[4]; const float* upw[4];
  for(int i=0;i<4;++i){ upidx[i] = (const int*)d_in[44+2*i]; upw[i] = (const float*)d_in[45+2*i]; }
  float* out = (float*)d_out;
  char* base = (char*)d_ws;

  float* A  = (float*)(base + BO_A);
  float* Bb = (float*)(base + BO_B);
  float* Cb = (float*)(base + BO_C);
  float* L3 = (float*)(base + BO_L3);
  float* L4 = (float*)(base + BO_L4);
  float* L5 = (float*)(base + BO_L5);
  float* L6 = (float*)(base + BO_L6);
  float* P5 = (float*)(base + BO_P5);
  float* Z  = (float*)(base + BO_Z);
  float* DX  = (float*)(base + BO_DX);
  float* DT1 = (float*)(base + BO_DT1);
  float* DT2 = (float*)(base + BO_DT2);
  float* DO_ = (float*)(base + BO_DO);
  float* DCAT= (float*)(base + BO_DCAT);
  float* DNRM= (float*)(base + BO_DNRM);
  float* DDEG= (float*)(base + BO_DDEG);

  // ============ Encoder (f32) ============
  // stage 1: 1->8 @ 16x192x192, fused res+pool(1,2,2) -> Bb [4,8,16,96,96]
  { ll n=(ll)B*8*16*192*192;
    k_conv1<<<gridFor(n),TPB,0,stream>>>(sax, w1[1], A, B,1,8,16,192,192);
    ll np=(ll)B*8*16*96*96;
    k_conv2respool<<<gridFor(np),TPB,0,stream>>>(A, sax, w2[1], wsk[1], Bb, B,8,8,1,16,192,192); }
  // stage 2: 8->16 @ 16x96x96, fused -> Cb [4,16,16,48,48]
  { ll n=(ll)B*16*16*96*96;
    k_conv1<<<gridFor(n),TPB,0,stream>>>(Bb, w1[2], A, B,8,16,16,96,96);
    ll np=(ll)B*16*16*48*48;
    k_conv2respool<<<gridFor(np),TPB,0,stream>>>(A, Bb, w2[2], wsk[2], Cb, B,16,16,8,16,96,96); }
  // stage 3: 16->32 @ 16x48x48 -> L3; pool(2,2,2) -> Bb
  { ll n=(ll)B*32*16*48*48;
    k_conv1<<<gridFor(n),TPB,0,stream>>>(Cb, w1[3], A, B,16,32,16,48,48);
    k_conv2res<<<gridFor(n),TPB,0,stream>>>(A, Cb, w2[3], wsk[3], L3, B,32,32,16,16,48,48);
    ll np=(ll)B*32*8*24*24;
    k_maxpool<<<gridFor(np),TPB,0,stream>>>(L3, Bb, B,32,16,48,48,2,2,2); }
  // stage 4: 32->64 @ 8x24x24 -> L4; pool(1,2,2) -> Cb
  { ll n=(ll)B*64*8*24*24;
    k_conv1<<<gridFor(n),TPB,0,stream>>>(Bb, w1[4], A, B,32,64,8,24,24);
    k_conv2res<<<gridFor(n),TPB,0,stream>>>(A, Bb, w2[4], wsk[4], L4, B,64,64,32,8,24,24);
    ll np=(ll)B*64*8*12*12;
    k_maxpool<<<gridFor(np),TPB,0,stream>>>(L4, Cb, B,64,8,24,24,1,2,2); }
  // stage 5: 64->128 @ 8x12x12 -> L5; pool(1,2,2) -> P5
  { ll n=(ll)B*128*8*12*12;
    k_conv1<<<gridFor(n),TPB,0,stream>>>(Cb, w1[5], A, B,64,128,8,12,12);
    k_conv2res<<<gridFor(n),TPB,0,stream>>>(A, Cb, w2[5], wsk[5], L5, B,128,128,64,8,12,12);
    ll np=(ll)B*128*8*6*6;
    k_maxpool<<<gridFor(np),TPB,0,stream>>>(L5, P5, B,128,8,12,12,1,2,2); }
  // stage 6: 128->128 @ 8x6x6, identity skip -> L6
  { ll n=(ll)B*128*8*6*6;
    k_conv1<<<gridFor(n),TPB,0,stream>>>(P5, w1[6], A, B,128,128,8,6,6);
    k_conv2res<<<gridFor(n),TPB,0,stream>>>(A, P5, w2[6], nullptr, L6, B,128,128,128,8,6,6); }

  // mu head: flat = P5 (pre-res6 pooled) [4,36864] @ mu_w^T -> Z
  k_linear_red<<<dim3(B*64),TPB,0,stream>>>(P5, mu_w, mu_b, Z, 36864, 64);
  // latent -> decoder: [4,88064] relu -> DX (overwrites arena A)
  k_ld<<<gridFor((ll)B*88064),TPB,0,stream>>>(Z, ld_w, ld_b, DX, B, 88064, 64);

  // ============ Decoder (f32) ============
  auto cheb = [&](float* xin, float* t1, float* t2, float* xout,
                  const int* e, int N, int E, const float* Wg, int Ci, int Co){
    const int* row = e; const int* col = e + E;
    ll BN = (ll)B*N;
    k_zero<<<gridFor(N),TPB,0,stream>>>(DDEG, N);
    k_deg<<<gridFor(E),TPB,0,stream>>>(row, DDEG, E);
    k_edgenorm<<<gridFor(E),TPB,0,stream>>>(row, col, DDEG, DNRM, E);
    // k = 0
    k_nodemm<<<gridFor(BN*Co),TPB,0,stream>>>(xin, Wg, xout, BN, Ci, Co, 0);
    // k = 1
    k_zero<<<gridFor(BN*Ci),TPB,0,stream>>>(t1, BN*Ci);
    k_scatter<<<gridFor((ll)B*E*Ci),TPB,0,stream>>>(xin, DNRM, row, col, t1, B,N,Ci,E);
    k_nodemm<<<gridFor(BN*Co),TPB,0,stream>>>(t1, Wg+(ll)Ci*Co, xout, BN, Ci, Co, 1);
    float *b0=xin, *b1=t1, *b2=t2;
    for(int k=2;k<6;++k){
      k_zero<<<gridFor(BN*Ci),TPB,0,stream>>>(b2, BN*Ci);
      k_scatter<<<gridFor((ll)B*E*Ci),TPB,0,stream>>>(b1, DNRM, row, col, b2, B,N,Ci,E);
      k_recur<<<gridFor(BN*Ci),TPB,0,stream>>>(b2, b0, BN*Ci);
      k_nodemm<<<gridFor(BN*Co),TPB,0,stream>>>(b2, Wg+(ll)k*Ci*Co, xout, BN, Ci, Co, 1);
      float* tmp=b0; b0=b1; b1=b2; b2=tmp;
    }
  };

  auto igsc = [&](float* x, float* cat, const float* ig, const float* feat,
                  int N, int Cx, int Cf, int D,int Hh,int Ww, float* ds){
    int Ctot = Cx + Cf + 3;
    ll BN = (ll)B*N;
    k_copycols<<<gridFor(BN*Cx),TPB,0,stream>>>(x, cat, BN, Cx, Ctot);
    k_pos<<<gridFor(BN),TPB,0,stream>>>(x, ig, cat, ds, BN, Cx, Ctot, Cx+Cf);
    k_gsample<<<gridFor(BN*(ll)Cf),TPB,0,stream>>>(feat, cat, B,N,Cf,D,Hh,Ww,Ctot,Cx,Cx+Cf);
  };

  // output layout: x[132000] ds4[66000] ds3[33000] ds2[16500] ds1[8256]
  float* out_x  = out;
  float* out_d4 = out + 132000;
  float* out_d3 = out + 198000;
  float* out_d2 = out + 231000;
  float* out_d1 = out + 247500;

  // stage 1: N=688, gc1 128->64, ig1 feat=L6, unpool3 -> 1375
  cheb(DX, DT1, DT2, DO_, edge[4], 688, 4128, gcw[0], 128, 64);
  k_inorm<<<gridFor((ll)B*688),TPB,0,stream>>>(DO_, gcb[0], (ll)B*688, 64);
  igsc(DO_, DCAT, igw[0], L6, 688, 64, 128, 8,6,6, out_d1);
  k_unpool<<<gridFor((ll)B*1375*195),TPB,0,stream>>>(DCAT, upidx[3], upw[3], DX, B, 688, 1375, 195);

  // stage 2: N=1375, gc2 195->64, ig2 feat=L5, unpool2 -> 2750
  cheb(DX, DT1, DT2, DO_, edge[3], 1375, 8250, gcw[1], 195, 64);
  k_inorm<<<gridFor((ll)B*1375),TPB,0,stream>>>(DO_, gcb[1], (ll)B*1375, 64);
  igsc(DO_, DCAT, igw[1], L5, 1375, 64, 128, 8,12,12, out_d2);
  k_unpool<<<gridFor((ll)B*2750*195),TPB,0,stream>>>(DCAT, upidx[2], upw[2], DX, B, 1375, 2750, 195);

  // stage 3: N=2750, gc3 195->32, ig3 feat=L4, unpool1 -> 5500
  cheb(DX, DT1, DT2, DO_, edge[2], 2750, 16500, gcw[2], 195, 32);
  k_inorm<<<gridFor((ll)B*2750),TPB,0,stream>>>(DO_, gcb[2], (ll)B*2750, 32);
  igsc(DO_, DCAT, igw[2], L4, 2750, 32, 64, 8,24,24, out_d3);
  k_unpool<<<gridFor((ll)B*5500*99),TPB,0,stream>>>(DCAT, upidx[1], upw[1], DX, B, 2750, 5500, 99);

  // stage 4: N=5500, gc4 99->32, ig4 feat=L3, unpool0 -> 11000
  cheb(DX, DT1, DT2, DO_, edge[1], 5500, 33000, gcw[3], 99, 32);
  k_inorm<<<gridFor((ll)B*5500),TPB,0,stream>>>(DO_, gcb[3], (ll)B*5500, 32);
  igsc(DO_, DCAT, igw[3], L3, 5500, 32, 32, 16,48,48, out_d4);
  k_unpool<<<gridFor((ll)B*11000*67),TPB,0,stream>>>(DCAT, upidx[0], upw[0], DX, B, 5500, 11000, 67);

  // stage 5: N=11000, gc5 67->32 (gconv with norm)
  cheb(DX, DT1, DT2, DO_, edge[0], 11000, 66000, gcw[4], 67, 32);
  k_inorm<<<gridFor((ll)B*11000),TPB,0,stream>>>(DO_, gcb[4], (ll)B*11000, 32);

  // GCout: 32->3, no bias, no norm -> DCAT, then copy to out
  cheb(DO_, DT1, DT2, DCAT, edge[0], 11000, 66000, gcout_w, 32, 3);
  k_copy<<<gridFor(132000LL),TPB,0,stream>>>(DCAT, out_x, 132000LL);
}

// Round 4
// 7507.526 us; speedup vs baseline: 1.8558x; 1.8558x over previous
//
#include <hip/hip_runtime.h>

typedef long long ll;

#define TPB 256

static inline dim3 gridFor(ll n){ return dim3((unsigned)((n + TPB - 1) / TPB)); }

// ---------------- misc ----------------
__global__ void k_zero(float* __restrict__ p, ll n){
  ll i = (ll)blockIdx.x*blockDim.x + threadIdx.x;
  if(i<n) p[i] = 0.f;
}
__global__ void k_copy(const float* __restrict__ in, float* __restrict__ out, ll n){
  ll i = (ll)blockIdx.x*blockDim.x + threadIdx.x;
  if(i<n) out[i] = in[i];
}

// ============ register-blocked conv kernels ============
// grid: (ceil(D*H*W/TPB), Co/COG, B); thread = one spatial pos, COG channels.
// Weight addresses are wave-uniform (cg=blockIdx.y) -> scalar loads.

template<int COG>
__global__ void k_conv1_t(const float* __restrict__ x, const float* __restrict__ w,
                          float* __restrict__ out, int Ci,int Co,int D,int H,int W)
{
  int HW = H*W, DHW = D*HW;
  int sp = blockIdx.x*blockDim.x + threadIdx.x;
  if(sp>=DHW) return;
  int cg = blockIdx.y, b = blockIdx.z;
  int wv = sp % W, hv = (sp/W) % H, dv = sp / HW;
  ll plane = (ll)DHW;
  const float* xb = x + ((ll)b*Ci)*plane;
  const float* wb = w + ((ll)cg*COG)*Ci*27;
  float acc[COG];
#pragma unroll
  for(int u=0;u<COG;++u) acc[u]=0.f;
  float vd[3],vh[3],vw[3]; int cd[3],ch[3],cw[3];
#pragma unroll
  for(int k=0;k<3;++k){
    int dd=dv+k-1; vd[k]=((unsigned)dd<(unsigned)D)?1.f:0.f; cd[k]=min(max(dd,0),D-1);
    int hh=hv+k-1; vh[k]=((unsigned)hh<(unsigned)H)?1.f:0.f; ch[k]=min(max(hh,0),H-1);
    int ww=wv+k-1; vw[k]=((unsigned)ww<(unsigned)W)?1.f:0.f; cw[k]=min(max(ww,0),W-1);
  }
  for(int ci=0;ci<Ci;++ci){
    const float* xc = xb + (ll)ci*plane;
    float xv[27];
#pragma unroll
    for(int kd=0;kd<3;++kd)
#pragma unroll
      for(int kh=0;kh<3;++kh){
        const float* rowp = xc + ((ll)cd[kd]*H + ch[kh])*W;
        float vdh = vd[kd]*vh[kh];
#pragma unroll
        for(int kw=0;kw<3;++kw)
          xv[(kd*3+kh)*3+kw] = rowp[cw[kw]]*(vdh*vw[kw]);
      }
    const float* wc = wb + ci*27;
#pragma unroll
    for(int u=0;u<COG;++u){
      const float* wu = wc + (ll)u*Ci*27;
      float a = acc[u];
#pragma unroll
      for(int kk=0;kk<27;++kk) a += xv[kk]*wu[kk];
      acc[u]=a;
    }
  }
  ll osp = sp;
#pragma unroll
  for(int u=0;u<COG;++u)
    out[((ll)b*Co + cg*COG+u)*plane + osp] = fmaxf(acc[u],0.f);
}

// conv2 + (1x1 skip | identity) + relu
template<int COG>
__global__ void k_conv2res_t(const float* __restrict__ cin, const float* __restrict__ xin,
                             const float* __restrict__ w2, const float* __restrict__ wsk,
                             float* __restrict__ out, int Cm,int Co,int Cs,int D,int H,int W)
{
  int HW = H*W, DHW = D*HW;
  int sp = blockIdx.x*blockDim.x + threadIdx.x;
  if(sp>=DHW) return;
  int cg = blockIdx.y, b = blockIdx.z;
  int wv = sp % W, hv = (sp/W) % H, dv = sp / HW;
  ll plane = (ll)DHW;
  float acc[COG];
  if(wsk){
    const float* xs = xin + ((ll)b*Cs)*plane + sp;
    const float* wr = wsk + (ll)cg*COG*Cs;
#pragma unroll
    for(int u=0;u<COG;++u) acc[u]=0.f;
    for(int cs=0;cs<Cs;++cs){
      float xv = xs[(ll)cs*plane];
#pragma unroll
      for(int u=0;u<COG;++u) acc[u] += xv*wr[(ll)u*Cs+cs];
    }
  } else {
#pragma unroll
    for(int u=0;u<COG;++u) acc[u] = xin[((ll)b*Co + cg*COG+u)*plane + sp];
  }
  float vd[3],vh[3],vw[3]; int cd[3],ch[3],cw[3];
#pragma unroll
  for(int k=0;k<3;++k){
    int dd=dv+k-1; vd[k]=((unsigned)dd<(unsigned)D)?1.f:0.f; cd[k]=min(max(dd,0),D-1);
    int hh=hv+k-1; vh[k]=((unsigned)hh<(unsigned)H)?1.f:0.f; ch[k]=min(max(hh,0),H-1);
    int ww=wv+k-1; vw[k]=((unsigned)ww<(unsigned)W)?1.f:0.f; cw[k]=min(max(ww,0),W-1);
  }
  const float* cb = cin + ((ll)b*Cm)*plane;
  const float* wb = w2 + ((ll)cg*COG)*Cm*27;
  for(int ci=0;ci<Cm;++ci){
    const float* xc = cb + (ll)ci*plane;
    float xv[27];
#pragma unroll
    for(int kd=0;kd<3;++kd)
#pragma unroll
      for(int kh=0;kh<3;++kh){
        const float* rowp = xc + ((ll)cd[kd]*H + ch[kh])*W;
        float vdh = vd[kd]*vh[kh];
#pragma unroll
        for(int kw=0;kw<3;++kw)
          xv[(kd*3+kh)*3+kw] = rowp[cw[kw]]*(vdh*vw[kw]);
      }
    const float* wc = wb + ci*27;
#pragma unroll
    for(int u=0;u<COG;++u){
      const float* wu = wc + (ll)u*Cm*27;
      float a = acc[u];
#pragma unroll
      for(int kk=0;kk<27;++kk) a += xv[kk]*wu[kk];
      acc[u]=a;
    }
  }
#pragma unroll
  for(int u=0;u<COG;++u)
    out[((ll)b*Co + cg*COG+u)*plane + sp] = fmaxf(acc[u],0.f);
}

// conv2 + 1x1 skip + relu + maxpool(1,2,2); spatial over pooled coords
template<int COG>
__global__ void k_conv2respool_t(const float* __restrict__ cin, const float* __restrict__ xin,
                                 const float* __restrict__ w2, const float* __restrict__ wsk,
                                 float* __restrict__ out, int Cm,int Co,int Cs,int D,int H,int W)
{
  int Ho=H/2, Wo=W/2;
  int HWo = Ho*Wo, DHWo = D*HWo;
  int sp = blockIdx.x*blockDim.x + threadIdx.x;
  if(sp>=DHWo) return;
  int cg = blockIdx.y, b = blockIdx.z;
  int wo = sp % Wo, ho = (sp/Wo) % Ho, dv = sp / HWo;
  ll plane = (ll)D*H*W;
  const float* cb = cin + ((ll)b*Cm)*plane;
  const float* xs = xin + ((ll)b*Cs)*plane;
  const float* wb = w2 + ((ll)cg*COG)*Cm*27;
  const float* wr = wsk + (ll)cg*COG*Cs;
  float m[COG];
#pragma unroll
  for(int u=0;u<COG;++u) m[u] = -3.4e38f;
  for(int py=0;py<2;++py){
    for(int px=0;px<2;++px){
      int hv=2*ho+py, wv=2*wo+px;
      ll spf = ((ll)dv*H+hv)*W+wv;
      float acc[COG];
#pragma unroll
      for(int u=0;u<COG;++u) acc[u]=0.f;
      for(int cs=0;cs<Cs;++cs){
        float xv = xs[(ll)cs*plane + spf];
#pragma unroll
        for(int u=0;u<COG;++u) acc[u] += xv*wr[(ll)u*Cs+cs];
      }
      float vd[3],vh[3],vw[3]; int cd[3],ch[3],cw[3];
#pragma unroll
      for(int k=0;k<3;++k){
        int dd=dv+k-1; vd[k]=((unsigned)dd<(unsigned)D)?1.f:0.f; cd[k]=min(max(dd,0),D-1);
        int hh=hv+k-1; vh[k]=((unsigned)hh<(unsigned)H)?1.f:0.f; ch[k]=min(max(hh,0),H-1);
        int ww=wv+k-1; vw[k]=((unsigned)ww<(unsigned)W)?1.f:0.f; cw[k]=min(max(ww,0),W-1);
      }
      for(int ci=0;ci<Cm;++ci){
        const float* xc = cb + (ll)ci*plane;
        float xv[27];
#pragma unroll
        for(int kd=0;kd<3;++kd)
#pragma unroll
          for(int kh=0;kh<3;++kh){
            const float* rowp = xc + ((ll)cd[kd]*H + ch[kh])*W;
            float vdh = vd[kd]*vh[kh];
#pragma unroll
            for(int kw=0;kw<3;++kw)
              xv[(kd*3+kh)*3+kw] = rowp[cw[kw]]*(vdh*vw[kw]);
          }
        const float* wc = wb + ci*27;
#pragma unroll
        for(int u=0;u<COG;++u){
          const float* wu = wc + (ll)u*Cm*27;
          float a = acc[u];
#pragma unroll
          for(int kk=0;kk<27;++kk) a += xv[kk]*wu[kk];
          acc[u]=a;
        }
      }
#pragma unroll
      for(int u=0;u<COG;++u) m[u] = fmaxf(m[u], fmaxf(acc[u],0.f));
    }
  }
#pragma unroll
  for(int u=0;u<COG;++u)
    out[(((ll)b*Co + cg*COG+u)*D+dv)*HWo + sp % HWo] = m[u];
}

// ---------------- maxpool3d (window==stride) ----------------
__global__ void k_maxpool(const float* __restrict__ x, float* __restrict__ out,
                          int B,int C,int D,int H,int W,int pd,int ph,int pw)
{
  int Do = D/pd, Ho = H/ph, Wo = W/pw;
  ll total = (ll)B*C*Do*Ho*Wo;
  ll i = (ll)blockIdx.x*blockDim.x + threadIdx.x;
  if(i>=total) return;
  int w0 = (int)(i % Wo); ll t = i / Wo;
  int h0 = (int)(t % Ho); t /= Ho;
  int d0 = (int)(t % Do); t /= Do;
  int c  = (int)(t % C);  int b = (int)(t / C);
  const float* xb = x + ((ll)b*C + c)*D*H*W;
  float m = -3.4e38f;
  for(int dd=0; dd<pd; ++dd)
    for(int hh=0; hh<ph; ++hh)
      for(int ww=0; ww<pw; ++ww){
        float v = xb[(((ll)(d0*pd+dd))*H + (h0*ph+hh))*W + (w0*pw+ww)];
        m = fmaxf(m, v);
      }
  out[i] = m;
}

// ---------------- mu linear with block reduction ----------------
__global__ void k_linear_red(const float* __restrict__ x, const float* __restrict__ w,
                             const float* __restrict__ bias, float* __restrict__ out,
                             int In, int Out)
{
  int o = blockIdx.x % Out;
  int b = blockIdx.x / Out;
  const float* xr = x + (ll)b*In;
  const float* wr = w + (ll)o*In;
  float s = 0.f;
  for(int i = threadIdx.x; i < In; i += blockDim.x) s += xr[i]*wr[i];
  __shared__ float red[TPB];
  red[threadIdx.x] = s; __syncthreads();
  for(int off = TPB/2; off > 0; off >>= 1){
    if(threadIdx.x < off) red[threadIdx.x] += red[threadIdx.x + off];
    __syncthreads();
  }
  if(threadIdx.x == 0) out[blockIdx.x] = red[0] + bias[o];
}

// ---------------- latent->decoder linear + relu ----------------
__global__ void k_ld(const float* __restrict__ z, const float* __restrict__ w,
                     const float* __restrict__ bias, float* __restrict__ out,
                     int B,int Out,int L)
{
  ll i = (ll)blockIdx.x*blockDim.x + threadIdx.x;
  if(i >= (ll)B*Out) return;
  int o = (int)(i % Out); int b = (int)(i / Out);
  const float* zr = z + (ll)b*L;
  const float* wr = w + (ll)o*L;
  float s = bias[o];
  for(int l=0; l<L; ++l) s += zr[l]*wr[l];
  out[i] = fmaxf(s, 0.f);
}

// ---------------- cheb graph helpers ----------------
__global__ void k_deg(const int* __restrict__ row, float* __restrict__ deg, int E){
  int e = blockIdx.x*blockDim.x + threadIdx.x;
  if(e<E) atomicAdd(&deg[row[e]], 1.f);
}
__global__ void k_edgenorm(const int* __restrict__ row, const int* __restrict__ col,
                           const float* __restrict__ deg, float* __restrict__ nrm, int E){
  int e = blockIdx.x*blockDim.x + threadIdx.x;
  if(e>=E) return;
  float dr = deg[row[e]], dc = deg[col[e]];
  float ir = dr > 0.f ? rsqrtf(dr) : 0.f;
  float ic = dc > 0.f ? rsqrtf(dc) : 0.f;
  nrm[e] = -(ir*ic);
}
__global__ void k_scatter(const float* __restrict__ v, const float* __restrict__ nrm,
                          const int* __restrict__ row, const int* __restrict__ col,
                          float* __restrict__ out, int B,int N,int C,int E)
{
  ll i = (ll)blockIdx.x*blockDim.x + threadIdx.x;
  ll total = (ll)B*E*C;
  if(i>=total) return;
  int c = (int)(i % C); ll t = i / C;
  int e = (int)(t % E); int b = (int)(t / E);
  float m = v[((ll)b*N + row[e])*C + c]*nrm[e];
  atomicAdd(&out[((ll)b*N + col[e])*C + c], m);
}
__global__ void k_recur(float* __restrict__ t2, const float* __restrict__ t0, ll n){
  ll i = (ll)blockIdx.x*blockDim.x + threadIdx.x;
  if(i<n) t2[i] = 2.f*t2[i] - t0[i];
}
__global__ void k_nodemm(const float* __restrict__ x, const float* __restrict__ w,
                         float* __restrict__ out, ll BN, int C, int F, int add)
{
  ll i = (ll)blockIdx.x*blockDim.x + threadIdx.x;
  if(i >= BN*(ll)F) return;
  int f = (int)(i % F); ll r = i / F;
  const float* xr = x + r*(ll)C;
  float s = add ? out[i] : 0.f;
  for(int c=0; c<C; ++c) s += xr[c]*w[(ll)c*F + f];
  out[i] = s;
}
__global__ void k_inorm(float* __restrict__ x, const float* __restrict__ bias, ll BN, int C)
{
  ll r = (ll)blockIdx.x*blockDim.x + threadIdx.x;
  if(r>=BN) return;
  float* xr = x + r*(ll)C;
  float mu = 0.f;
  for(int c=0;c<C;++c){ float v = xr[c] + bias[c]; xr[c]=v; mu += v; }
  mu /= (float)C;
  float var = 0.f;
  for(int c=0;c<C;++c){ float d = xr[c]-mu; var += d*d; }
  var /= (float)C;
  float inv = rsqrtf(var + 1e-5f);
  for(int c=0;c<C;++c) xr[c] = fmaxf((xr[c]-mu)*inv, 0.f);
}

// ---------------- IGSC ----------------
__global__ void k_copycols(const float* __restrict__ x, float* __restrict__ cat,
                           ll BN, int Cx, int Ctot)
{
  ll i = (ll)blockIdx.x*blockDim.x + threadIdx.x;
  if(i >= BN*(ll)Cx) return;
  int c = (int)(i % Cx); ll r = i / Cx;
  cat[r*(ll)Ctot + c] = x[i];
}
__global__ void k_pos(const float* __restrict__ x, const float* __restrict__ igw,
                      float* __restrict__ cat, float* __restrict__ ds,
                      ll BN, int Cx, int Ctot, int posoff)
{
  ll i = (ll)blockIdx.x*blockDim.x + threadIdx.x;
  if(i>=BN) return;
  const float* xr = x + i*(ll)Cx;
  float p0=0.f,p1=0.f,p2=0.f;
  for(int c=0;c<Cx;++c){
    float v = xr[c];
    p0 += v*igw[c*3+0];
    p1 += v*igw[c*3+1];
    p2 += v*igw[c*3+2];
  }
  float* rowp = cat + i*(ll)Ctot + posoff;
  rowp[0]=p0; rowp[1]=p1; rowp[2]=p2;
  ds[i*3+0]=p0; ds[i*3+1]=p1; ds[i*3+2]=p2;
}
__global__ void k_gsample(const float* __restrict__ feat, float* __restrict__ cat,
                          int B,int N,int Cf,int D,int H,int W,int Ctot,int xoff,int posoff)
{
  ll i = (ll)blockIdx.x*blockDim.x + threadIdx.x;
  ll total = (ll)B*N*Cf;
  if(i>=total) return;
  int c = (int)(i % Cf); ll t = i / Cf;
  int n = (int)(t % N); int b = (int)(t / N);
  float* rowp = cat + ((ll)b*N + n)*Ctot;
  float px = rowp[posoff+0], py = rowp[posoff+1], pz = rowp[posoff+2];
  float gx = (2.f*px - 1.f + 1.f)*0.5f*(W-1);
  float gy = (2.f*py - 1.f + 1.f)*0.5f*(H-1);
  float gz = (2.f*pz - 1.f + 1.f)*0.5f*(D-1);
  float x0 = floorf(gx), y0 = floorf(gy), z0 = floorf(gz);
  const float* fb = feat + ((ll)b*Cf + c)*D*H*W;
  float acc = 0.f;
  for(int dz=0; dz<2; ++dz)
    for(int dy=0; dy<2; ++dy)
      for(int dx=0; dx<2; ++dx){
        float xi = x0+dx, yi = y0+dy, zi = z0+dz;
        float wgt = (1.f-fabsf(gx-xi))*(1.f-fabsf(gy-yi))*(1.f-fabsf(gz-zi));
        bool valid = (xi>=0.f)&&(xi<=(float)(W-1))&&(yi>=0.f)&&(yi<=(float)(H-1))&&(zi>=0.f)&&(zi<=(float)(D-1));
        int xc = min(max((int)xi,0),W-1);
        int yc = min(max((int)yi,0),H-1);
        int zc = min(max((int)zi,0),D-1);
        if(valid) acc += fb[((ll)zc*H + yc)*W + xc]*wgt;
      }
  rowp[xoff + c] = acc;
}

// ---------------- unpool ----------------
__global__ void k_unpool(const float* __restrict__ xin, const int* __restrict__ idx,
                         const float* __restrict__ w, float* __restrict__ out,
                         int B,int Ni,int No,int C)
{
  ll i = (ll)blockIdx.x*blockDim.x + threadIdx.x;
  ll total = (ll)B*No*C;
  if(i>=total) return;
  int c = (int)(i % C); ll t = i / C;
  int no = (int)(t % No); int b = (int)(t / No);
  float s = 0.f;
  for(int k=0;k<3;++k){
    s += xin[((ll)b*Ni + idx[no*3+k])*C + c]*w[no*3+k];
  }
  out[i] = s;
}

// ================= workspace layout (BYTE offsets, total ~126 MiB) =================
static const ll BO_A   = 0;            // f32 scratch, cap 18,874,368 fl; decoder arena
static const ll BO_B   = 75497472;     // f32, cap 4,718,592 fl
static const ll BO_C   = 94371840;     // f32, cap 2,359,296 fl
static const ll BO_L3  = 103809024;    // 4,718,592 fl
static const ll BO_L4  = 122683392;    // 1,179,648 fl
static const ll BO_L5  = 127401984;    //   589,824 fl
static const ll BO_L6  = 129761280;    //   294,912 fl
static const ll BO_P5  = 130940928;    //   294,912 fl
static const ll BO_Z   = 132120576;    // 256 fl
// decoder f32 regions inside arena A
static const ll BO_DX   = 0;
static const ll BO_DT1  = 11792000;
static const ll BO_DT2  = 23584000;
static const ll BO_DO   = 35376000;
static const ll BO_DCAT = 41008000;
static const ll BO_DNRM = 46904000;
static const ll BO_DDEG = 47168000;

extern "C" void kernel_launch(void* const* d_in, const int* in_sizes, int n_in,
                              void* d_out, int out_size, void* d_ws, size_t ws_size,
                              hipStream_t stream)
{
  (void)in_sizes; (void)n_in; (void)out_size; (void)ws_size;
  const int B = 4;
  const float* sax = (const float*)d_in[0];
  const float *w1[7], *w2[7], *wsk[7];
  for(int i=1;i<=5;++i){
    w1[i]  = (const float*)d_in[1 + (i-1)*3];
    w2[i]  = (const float*)d_in[2 + (i-1)*3];
    wsk[i] = (const float*)d_in[3 + (i-1)*3];
  }
  w1[6] = (const float*)d_in[16]; w2[6] = (const float*)d_in[17]; wsk[6] = nullptr;
  const float* mu_w = (const float*)d_in[18];
  const float* mu_b = (const float*)d_in[19];
  const float* ld_w = (const float*)d_in[22];
  const float* ld_b = (const float*)d_in[23];
  const float *gcw[5], *gcb[5];
  for(int i=0;i<5;++i){ gcw[i] = (const float*)d_in[24+2*i]; gcb[i] = (const float*)d_in[25+2*i]; }
  const float* gcout_w = (const float*)d_in[34];
  const float* igw[4];
  for(int i=0;i<4;++i) igw[i] = (const float*)d_in[35+i];
  const int* edge[5];
  for(int i=0;i<5;++i) edge[i] = (const int*)d_in[39+i];
  const int* upidx[4]; const float* upw[4];
  for(int i=0;i<4;++i){ upidx[i] = (const int*)d_in[44+2*i]; upw[i] = (const float*)d_in[45+2*i]; }
  float* out = (float*)d_out;
  char* base = (char*)d_ws;

  float* A  = (float*)(base + BO_A);
  float* Bb = (float*)(base + BO_B);
  float* Cb = (float*)(base + BO_C);
  float* L3 = (float*)(base + BO_L3);
  float* L4 = (float*)(base + BO_L4);
  float* L5 = (float*)(base + BO_L5);
  float* L6 = (float*)(base + BO_L6);
  float* P5 = (float*)(base + BO_P5);
  float* Z  = (float*)(base + BO_Z);
  float* DX  = (float*)(base + BO_DX);
  float* DT1 = (float*)(base + BO_DT1);
  float* DT2 = (float*)(base + BO_DT2);
  float* DO_ = (float*)(base + BO_DO);
  float* DCAT= (float*)(base + BO_DCAT);
  float* DNRM= (float*)(base + BO_DNRM);
  float* DDEG= (float*)(base + BO_DDEG);

  // ============ Encoder (f32, register-blocked convs) ============
  auto convgrid = [&](int DHW, int Co, int COG){ return dim3((unsigned)((DHW+TPB-1)/TPB), Co/COG, B); };

  // stage 1: 1->8 @ 16x192x192; fused res+pool -> Bb [4,8,16,96,96]
  k_conv1_t<8><<<convgrid(16*192*192,8,8),TPB,0,stream>>>(sax, w1[1], A, 1,8,16,192,192);
  k_conv2respool_t<8><<<convgrid(16*96*96,8,8),TPB,0,stream>>>(A, sax, w2[1], wsk[1], Bb, 8,8,1,16,192,192);
  // stage 2: 8->16 @ 16x96x96; fused -> Cb [4,16,16,48,48]
  k_conv1_t<8><<<convgrid(16*96*96,16,8),TPB,0,stream>>>(Bb, w1[2], A, 8,16,16,96,96);
  k_conv2respool_t<8><<<convgrid(16*48*48,16,8),TPB,0,stream>>>(A, Bb, w2[2], wsk[2], Cb, 16,16,8,16,96,96);
  // stage 3: 16->32 @ 16x48x48 -> L3; pool(2,2,2) -> Bb
  k_conv1_t<8><<<convgrid(16*48*48,32,8),TPB,0,stream>>>(Cb, w1[3], A, 16,32,16,48,48);
  k_conv2res_t<8><<<convgrid(16*48*48,32,8),TPB,0,stream>>>(A, Cb, w2[3], wsk[3], L3, 32,32,16,16,48,48);
  { ll np=(ll)B*32*8*24*24;
    k_maxpool<<<gridFor(np),TPB,0,stream>>>(L3, Bb, B,32,16,48,48,2,2,2); }
  // stage 4: 32->64 @ 8x24x24 -> L4; pool(1,2,2) -> Cb
  k_conv1_t<8><<<convgrid(8*24*24,64,8),TPB,0,stream>>>(Bb, w1[4], A, 32,64,8,24,24);
  k_conv2res_t<8><<<convgrid(8*24*24,64,8),TPB,0,stream>>>(A, Bb, w2[4], wsk[4], L4, 64,64,32,8,24,24);
  { ll np=(ll)B*64*8*12*12;
    k_maxpool<<<gridFor(np),TPB,0,stream>>>(L4, Cb, B,64,8,24,24,1,2,2); }
  // stage 5: 64->128 @ 8x12x12 -> L5; pool(1,2,2) -> P5
  k_conv1_t<8><<<convgrid(8*12*12,128,8),TPB,0,stream>>>(Cb, w1[5], A, 64,128,8,12,12);
  k_conv2res_t<8><<<convgrid(8*12*12,128,8),TPB,0,stream>>>(A, Cb, w2[5], wsk[5], L5, 128,128,64,8,12,12);
  { ll np=(ll)B*128*8*6*6;
    k_maxpool<<<gridFor(np),TPB,0,stream>>>(L5, P5, B,128,8,12,12,1,2,2); }
  // stage 6: 128->128 @ 8x6x6, identity skip -> L6 (COG=4 for thread count)
  k_conv1_t<4><<<convgrid(8*6*6,128,4),TPB,0,stream>>>(P5, w1[6], A, 128,128,8,6,6);
  k_conv2res_t<4><<<convgrid(8*6*6,128,4),TPB,0,stream>>>(A, P5, w2[6], nullptr, L6, 128,128,128,8,6,6);

  // mu head
  k_linear_red<<<dim3(B*64),TPB,0,stream>>>(P5, mu_w, mu_b, Z, 36864, 64);
  // latent -> decoder
  k_ld<<<gridFor((ll)B*88064),TPB,0,stream>>>(Z, ld_w, ld_b, DX, B, 88064, 64);

  // ============ Decoder (f32) ============
  auto cheb = [&](float* xin, float* t1, float* t2, float* xout,
                  const int* e, int N, int E, const float* Wg, int Ci, int Co){
    const int* row = e; const int* col = e + E;
    ll BN = (ll)B*N;
    k_zero<<<gridFor(N),TPB,0,stream>>>(DDEG, N);
    k_deg<<<gridFor(E),TPB,0,stream>>>(row, DDEG, E);
    k_edgenorm<<<gridFor(E),TPB,0,stream>>>(row, col, DDEG, DNRM, E);
    k_nodemm<<<gridFor(BN*Co),TPB,0,stream>>>(xin, Wg, xout, BN, Ci, Co, 0);
    k_zero<<<gridFor(BN*Ci),TPB,0,stream>>>(t1, BN*Ci);
    k_scatter<<<gridFor((ll)B*E*Ci),TPB,0,stream>>>(xin, DNRM, row, col, t1, B,N,Ci,E);
    k_nodemm<<<gridFor(BN*Co),TPB,0,stream>>>(t1, Wg+(ll)Ci*Co, xout, BN, Ci, Co, 1);
    float *b0=xin, *b1=t1, *b2=t2;
    for(int k=2;k<6;++k){
      k_zero<<<gridFor(BN*Ci),TPB,0,stream>>>(b2, BN*Ci);
      k_scatter<<<gridFor((ll)B*E*Ci),TPB,0,stream>>>(b1, DNRM, row, col, b2, B,N,Ci,E);
      k_recur<<<gridFor(BN*Ci),TPB,0,stream>>>(b2, b0, BN*Ci);
      k_nodemm<<<gridFor(BN*Co),TPB,0,stream>>>(b2, Wg+(ll)k*Ci*Co, xout, BN, Ci, Co, 1);
      float* tmp=b0; b0=b1; b1=b2; b2=tmp;
    }
  };

  auto igsc = [&](float* x, float* cat, const float* ig, const float* feat,
                  int N, int Cx, int Cf, int D,int Hh,int Ww, float* ds){
    int Ctot = Cx + Cf + 3;
    ll BN = (ll)B*N;
    k_copycols<<<gridFor(BN*Cx),TPB,0,stream>>>(x, cat, BN, Cx, Ctot);
    k_pos<<<gridFor(BN),TPB,0,stream>>>(x, ig, cat, ds, BN, Cx, Ctot, Cx+Cf);
    k_gsample<<<gridFor(BN*(ll)Cf),TPB,0,stream>>>(feat, cat, B,N,Cf,D,Hh,Ww,Ctot,Cx,Cx+Cf);
  };

  float* out_x  = out;
  float* out_d4 = out + 132000;
  float* out_d3 = out + 198000;
  float* out_d2 = out + 231000;
  float* out_d1 = out + 247500;

  cheb(DX, DT1, DT2, DO_, edge[4], 688, 4128, gcw[0], 128, 64);
  k_inorm<<<gridFor((ll)B*688),TPB,0,stream>>>(DO_, gcb[0], (ll)B*688, 64);
  igsc(DO_, DCAT, igw[0], L6, 688, 64, 128, 8,6,6, out_d1);
  k_unpool<<<gridFor((ll)B*1375*195),TPB,0,stream>>>(DCAT, upidx[3], upw[3], DX, B, 688, 1375, 195);

  cheb(DX, DT1, DT2, DO_, edge[3], 1375, 8250, gcw[1], 195, 64);
  k_inorm<<<gridFor((ll)B*1375),TPB,0,stream>>>(DO_, gcb[1], (ll)B*1375, 64);
  igsc(DO_, DCAT, igw[1], L5, 1375, 64, 128, 8,12,12, out_d2);
  k_unpool<<<gridFor((ll)B*2750*195),TPB,0,stream>>>(DCAT, upidx[2], upw[2], DX, B, 1375, 2750, 195);

  cheb(DX, DT1, DT2, DO_, edge[2], 2750, 16500, gcw[2], 195, 32);
  k_inorm<<<gridFor((ll)B*2750),TPB,0,stream>>>(DO_, gcb[2], (ll)B*2750, 32);
  igsc(DO_, DCAT, igw[2], L4, 2750, 32, 64, 8,24,24, out_d3);
  k_unpool<<<gridFor((ll)B*5500*99),TPB,0,stream>>>(DCAT, upidx[1], upw[1], DX, B, 2750, 5500, 99);

  cheb(DX, DT1, DT2, DO_, edge[1], 5500, 33000, gcw[3], 99, 32);
  k_inorm<<<gridFor((ll)B*5500),TPB,0,stream>>>(DO_, gcb[3], (ll)B*5500, 32);
  igsc(DO_, DCAT, igw[3], L3, 5500, 32, 32, 16,48,48, out_d4);
  k_unpool<<<gridFor((ll)B*11000*67),TPB,0,stream>>>(DCAT, upidx[0], upw[0], DX, B, 5500, 11000, 67);

  cheb(DX, DT1, DT2, DO_, edge[0], 11000, 66000, gcw[4], 67, 32);
  k_inorm<<<gridFor((ll)B*11000),TPB,0,stream>>>(DO_, gcb[4], (ll)B*11000, 32);

  cheb(DO_, DT1, DT2, DCAT, edge[0], 11000, 66000, gcout_w, 32, 3);
  k_copy<<<gridFor(132000LL),TPB,0,stream>>>(DCAT, out_x, 132000LL);
}

// Round 6
// 6618.407 us; speedup vs baseline: 2.1051x; 1.1343x over previous
//
#include <hip/hip_runtime.h>

typedef long long ll;

#define TPB 256

static inline dim3 gridFor(ll n){ return dim3((unsigned)((n + TPB - 1) / TPB)); }

// ---------------- misc ----------------
__global__ void k_copy(const float* __restrict__ in, float* __restrict__ out, ll n){
  ll i = (ll)blockIdx.x*blockDim.x + threadIdx.x;
  if(i<n) out[i] = in[i];
}

// ============ register-blocked conv kernels ============
template<int COG>
__global__ void k_conv1_t(const float* __restrict__ x, const float* __restrict__ w,
                          float* __restrict__ out, int Ci,int Co,int D,int H,int W)
{
  int HW = H*W, DHW = D*HW;
  int sp = blockIdx.x*blockDim.x + threadIdx.x;
  if(sp>=DHW) return;
  int cg = blockIdx.y, b = blockIdx.z;
  int wv = sp % W, hv = (sp/W) % H, dv = sp / HW;
  ll plane = (ll)DHW;
  const float* xb = x + ((ll)b*Ci)*plane;
  const float* wb = w + ((ll)cg*COG)*Ci*27;
  float acc[COG];
#pragma unroll
  for(int u=0;u<COG;++u) acc[u]=0.f;
  float vd[3],vh[3],vw[3]; int cd[3],ch[3],cw[3];
#pragma unroll
  for(int k=0;k<3;++k){
    int dd=dv+k-1; vd[k]=((unsigned)dd<(unsigned)D)?1.f:0.f; cd[k]=min(max(dd,0),D-1);
    int hh=hv+k-1; vh[k]=((unsigned)hh<(unsigned)H)?1.f:0.f; ch[k]=min(max(hh,0),H-1);
    int ww=wv+k-1; vw[k]=((unsigned)ww<(unsigned)W)?1.f:0.f; cw[k]=min(max(ww,0),W-1);
  }
  for(int ci=0;ci<Ci;++ci){
    const float* xc = xb + (ll)ci*plane;
    float xv[27];
#pragma unroll
    for(int kd=0;kd<3;++kd)
#pragma unroll
      for(int kh=0;kh<3;++kh){
        const float* rowp = xc + ((ll)cd[kd]*H + ch[kh])*W;
        float vdh = vd[kd]*vh[kh];
#pragma unroll
        for(int kw=0;kw<3;++kw)
          xv[(kd*3+kh)*3+kw] = rowp[cw[kw]]*(vdh*vw[kw]);
      }
    const float* wc = wb + ci*27;
#pragma unroll
    for(int u=0;u<COG;++u){
      const float* wu = wc + (ll)u*Ci*27;
      float a = acc[u];
#pragma unroll
      for(int kk=0;kk<27;++kk) a += xv[kk]*wu[kk];
      acc[u]=a;
    }
  }
#pragma unroll
  for(int u=0;u<COG;++u)
    out[((ll)b*Co + cg*COG+u)*plane + sp] = fmaxf(acc[u],0.f);
}

template<int COG>
__global__ void k_conv2res_t(const float* __restrict__ cin, const float* __restrict__ xin,
                             const float* __restrict__ w2, const float* __restrict__ wsk,
                             float* __restrict__ out, int Cm,int Co,int Cs,int D,int H,int W)
{
  int HW = H*W, DHW = D*HW;
  int sp = blockIdx.x*blockDim.x + threadIdx.x;
  if(sp>=DHW) return;
  int cg = blockIdx.y, b = blockIdx.z;
  int wv = sp % W, hv = (sp/W) % H, dv = sp / HW;
  ll plane = (ll)DHW;
  float acc[COG];
  if(wsk){
    const float* xs = xin + ((ll)b*Cs)*plane + sp;
    const float* wr = wsk + (ll)cg*COG*Cs;
#pragma unroll
    for(int u=0;u<COG;++u) acc[u]=0.f;
    for(int cs=0;cs<Cs;++cs){
      float xv = xs[(ll)cs*plane];
#pragma unroll
      for(int u=0;u<COG;++u) acc[u] += xv*wr[(ll)u*Cs+cs];
    }
  } else {
#pragma unroll
    for(int u=0;u<COG;++u) acc[u] = xin[((ll)b*Co + cg*COG+u)*plane + sp];
  }
  float vd[3],vh[3],vw[3]; int cd[3],ch[3],cw[3];
#pragma unroll
  for(int k=0;k<3;++k){
    int dd=dv+k-1; vd[k]=((unsigned)dd<(unsigned)D)?1.f:0.f; cd[k]=min(max(dd,0),D-1);
    int hh=hv+k-1; vh[k]=((unsigned)hh<(unsigned)H)?1.f:0.f; ch[k]=min(max(hh,0),H-1);
    int ww=wv+k-1; vw[k]=((unsigned)ww<(unsigned)W)?1.f:0.f; cw[k]=min(max(ww,0),W-1);
  }
  const float* cb = cin + ((ll)b*Cm)*plane;
  const float* wb = w2 + ((ll)cg*COG)*Cm*27;
  for(int ci=0;ci<Cm;++ci){
    const float* xc = cb + (ll)ci*plane;
    float xv[27];
#pragma unroll
    for(int kd=0;kd<3;++kd)
#pragma unroll
      for(int kh=0;kh<3;++kh){
        const float* rowp = xc + ((ll)cd[kd]*H + ch[kh])*W;
        float vdh = vd[kd]*vh[kh];
#pragma unroll
        for(int kw=0;kw<3;++kw)
          xv[(kd*3+kh)*3+kw] = rowp[cw[kw]]*(vdh*vw[kw]);
      }
    const float* wc = wb + ci*27;
#pragma unroll
    for(int u=0;u<COG;++u){
      const float* wu = wc + (ll)u*Cm*27;
      float a = acc[u];
#pragma unroll
      for(int kk=0;kk<27;++kk) a += xv[kk]*wu[kk];
      acc[u]=a;
    }
  }
#pragma unroll
  for(int u=0;u<COG;++u)
    out[((ll)b*Co + cg*COG+u)*plane + sp] = fmaxf(acc[u],0.f);
}

template<int COG>
__global__ void k_conv2respool_t(const float* __restrict__ cin, const float* __restrict__ xin,
                                 const float* __restrict__ w2, const float* __restrict__ wsk,
                                 float* __restrict__ out, int Cm,int Co,int Cs,int D,int H,int W)
{
  int Ho=H/2, Wo=W/2;
  int HWo = Ho*Wo, DHWo = D*HWo;
  int sp = blockIdx.x*blockDim.x + threadIdx.x;
  if(sp>=DHWo) return;
  int cg = blockIdx.y, b = blockIdx.z;
  int wo = sp % Wo, ho = (sp/Wo) % Ho, dv = sp / HWo;
  ll plane = (ll)D*H*W;
  const float* cb = cin + ((ll)b*Cm)*plane;
  const float* xs = xin + ((ll)b*Cs)*plane;
  const float* wb = w2 + ((ll)cg*COG)*Cm*27;
  const float* wr = wsk + (ll)cg*COG*Cs;
  float m[COG];
#pragma unroll
  for(int u=0;u<COG;++u) m[u] = -3.4e38f;
  for(int py=0;py<2;++py){
    for(int px=0;px<2;++px){
      int hv=2*ho+py, wv=2*wo+px;
      ll spf = ((ll)dv*H+hv)*W+wv;
      float acc[COG];
#pragma unroll
      for(int u=0;u<COG;++u) acc[u]=0.f;
      for(int cs=0;cs<Cs;++cs){
        float xv = xs[(ll)cs*plane + spf];
#pragma unroll
        for(int u=0;u<COG;++u) acc[u] += xv*wr[(ll)u*Cs+cs];
      }
      float vd[3],vh[3],vw[3]; int cd[3],ch[3],cw[3];
#pragma unroll
      for(int k=0;k<3;++k){
        int dd=dv+k-1; vd[k]=((unsigned)dd<(unsigned)D)?1.f:0.f; cd[k]=min(max(dd,0),D-1);
        int hh=hv+k-1; vh[k]=((unsigned)hh<(unsigned)H)?1.f:0.f; ch[k]=min(max(hh,0),H-1);
        int ww=wv+k-1; vw[k]=((unsigned)ww<(unsigned)W)?1.f:0.f; cw[k]=min(max(ww,0),W-1);
      }
      for(int ci=0;ci<Cm;++ci){
        const float* xc = cb + (ll)ci*plane;
        float xv[27];
#pragma unroll
        for(int kd=0;kd<3;++kd)
#pragma unroll
          for(int kh=0;kh<3;++kh){
            const float* rowp = xc + ((ll)cd[kd]*H + ch[kh])*W;
            float vdh = vd[kd]*vh[kh];
#pragma unroll
            for(int kw=0;kw<3;++kw)
              xv[(kd*3+kh)*3+kw] = rowp[cw[kw]]*(vdh*vw[kw]);
          }
        const float* wc = wb + ci*27;
#pragma unroll
        for(int u=0;u<COG;++u){
          const float* wu = wc + (ll)u*Cm*27;
          float a = acc[u];
#pragma unroll
          for(int kk=0;kk<27;++kk) a += xv[kk]*wu[kk];
          acc[u]=a;
        }
      }
#pragma unroll
      for(int u=0;u<COG;++u) m[u] = fmaxf(m[u], fmaxf(acc[u],0.f));
    }
  }
#pragma unroll
  for(int u=0;u<COG;++u)
    out[(((ll)b*Co + cg*COG+u)*D+dv)*HWo + sp % HWo] = m[u];
}

// ---------------- maxpool3d ----------------
__global__ void k_maxpool(const float* __restrict__ x, float* __restrict__ out,
                          int B,int C,int D,int H,int W,int pd,int ph,int pw)
{
  int Do = D/pd, Ho = H/ph, Wo = W/pw;
  ll total = (ll)B*C*Do*Ho*Wo;
  ll i = (ll)blockIdx.x*blockDim.x + threadIdx.x;
  if(i>=total) return;
  int w0 = (int)(i % Wo); ll t = i / Wo;
  int h0 = (int)(t % Ho); t /= Ho;
  int d0 = (int)(t % Do); t /= Do;
  int c  = (int)(t % C);  int b = (int)(t / C);
  const float* xb = x + ((ll)b*C + c)*D*H*W;
  float m = -3.4e38f;
  for(int dd=0; dd<pd; ++dd)
    for(int hh=0; hh<ph; ++hh)
      for(int ww=0; ww<pw; ++ww){
        float v = xb[(((ll)(d0*pd+dd))*H + (h0*ph+hh))*W + (w0*pw+ww)];
        m = fmaxf(m, v);
      }
  out[i] = m;
}

// ---------------- mu linear ----------------
__global__ void k_linear_red(const float* __restrict__ x, const float* __restrict__ w,
                             const float* __restrict__ bias, float* __restrict__ out,
                             int In, int Out)
{
  int o = blockIdx.x % Out;
  int b = blockIdx.x / Out;
  const float* xr = x + (ll)b*In;
  const float* wr = w + (ll)o*In;
  float s = 0.f;
  for(int i = threadIdx.x; i < In; i += blockDim.x) s += xr[i]*wr[i];
  __shared__ float red[TPB];
  red[threadIdx.x] = s; __syncthreads();
  for(int off = TPB/2; off > 0; off >>= 1){
    if(threadIdx.x < off) red[threadIdx.x] += red[threadIdx.x + off];
    __syncthreads();
  }
  if(threadIdx.x == 0) out[blockIdx.x] = red[0] + bias[o];
}

// ---------------- latent->decoder linear + relu ----------------
__global__ void k_ld(const float* __restrict__ z, const float* __restrict__ w,
                     const float* __restrict__ bias, float* __restrict__ out,
                     int B,int Out,int L)
{
  ll i = (ll)blockIdx.x*blockDim.x + threadIdx.x;
  if(i >= (ll)B*Out) return;
  int o = (int)(i % Out); int b = (int)(i / Out);
  const float* zr = z + (ll)b*L;
  const float* wr = w + (ll)o*L;
  float s = bias[o];
  for(int l=0; l<L; ++l) s += zr[l]*wr[l];
  out[i] = fmaxf(s, 0.f);
}

// ================= CSR-based Chebyshev graph ops =================
__global__ void k_zero2(float* __restrict__ deg, int* __restrict__ cnt, int N){
  int i = blockIdx.x*blockDim.x + threadIdx.x;
  if(i<N){ deg[i]=0.f; cnt[i]=0; }
}
__global__ void k_degcnt(const int* __restrict__ row, const int* __restrict__ col,
                         float* __restrict__ deg, int* __restrict__ cnt, int E){
  int e = blockIdx.x*blockDim.x + threadIdx.x;
  if(e>=E) return;
  atomicAdd(&deg[row[e]], 1.f);
  atomicAdd(&cnt[col[e]], 1);
}
// single-block exclusive scan of cnt -> rowptr[0..N], cursor=rowptr[0..N-1]
__global__ void k_scan(const int* __restrict__ cnt, int* __restrict__ rowptr,
                       int* __restrict__ cursor, int N)
{
  __shared__ int ps[TPB];
  int t = threadIdx.x;
  int chunk = (N + TPB - 1)/TPB;
  int s0 = t*chunk, s1 = min(s0+chunk, N);
  int sum = 0;
  for(int i=s0;i<s1;++i) sum += cnt[i];
  ps[t] = sum; __syncthreads();
  for(int off=1; off<TPB; off<<=1){
    int v = (t>=off)? ps[t-off] : 0; __syncthreads();
    ps[t] += v; __syncthreads();
  }
  int base = (t==0)? 0 : ps[t-1];
  for(int i=s0;i<s1;++i){ rowptr[i]=base; cursor[i]=base; base += cnt[i]; }
  if(s1==N) rowptr[N]=base;
}
// fill CSR: src (row id) and weight (-dinv[row]*dinv[col]) grouped by col
__global__ void k_fill(const int* __restrict__ row, const int* __restrict__ col,
                       const float* __restrict__ deg, int* __restrict__ cursor,
                       int* __restrict__ src, float* __restrict__ wgt, int E)
{
  int e = blockIdx.x*blockDim.x + threadIdx.x;
  if(e>=E) return;
  int r = row[e], c = col[e];
  float dr = deg[r], dc = deg[c];
  float ir = dr > 0.f ? rsqrtf(dr) : 0.f;
  float ic = dc > 0.f ? rsqrtf(dc) : 0.f;
  int pos = atomicAdd(&cursor[c], 1);
  src[pos] = r;
  wgt[pos] = -(ir*ic);
}
// gather: out[b,j,c] = (mode? 2*S-t0 : S),  S = sum_{e in col==j} v[b,src[e],c]*wgt[e]
__global__ void k_gather(const float* __restrict__ v, const float* __restrict__ t0,
                         const int* __restrict__ rowptr, const int* __restrict__ src,
                         const float* __restrict__ wgt, float* __restrict__ out,
                         int B, int N, int C, int mode)
{
  ll i = (ll)blockIdx.x*blockDim.x + threadIdx.x;
  ll total = (ll)B*N*C;
  if(i>=total) return;
  int c = (int)(i % C); ll t = i / C;
  int j = (int)(t % N); int b = (int)(t / N);
  int e0 = rowptr[j], e1 = rowptr[j+1];
  float s = 0.f;
  const float* vb = v + (ll)b*N*C;
  for(int e=e0;e<e1;++e) s += vb[(ll)src[e]*C + c]*wgt[e];
  if(mode) s = 2.f*s - t0[i];
  out[i] = s;
}
// out[r,f] (+)= sum_c x[r,c]*w[c,f]
__global__ void k_nodemm(const float* __restrict__ x, const float* __restrict__ w,
                         float* __restrict__ out, ll BN, int C, int F, int add)
{
  ll i = (ll)blockIdx.x*blockDim.x + threadIdx.x;
  if(i >= BN*(ll)F) return;
  int f = (int)(i % F); ll r = i / F;
  const float* xr = x + r*(ll)C;
  float s = add ? out[i] : 0.f;
  for(int c=0; c<C; ++c) s += xr[c]*w[(ll)c*F + f];
  out[i] = s;
}
__global__ void k_inorm(float* __restrict__ x, const float* __restrict__ bias, ll BN, int C)
{
  ll r = (ll)blockIdx.x*blockDim.x + threadIdx.x;
  if(r>=BN) return;
  float* xr = x + r*(ll)C;
  float mu = 0.f;
  for(int c=0;c<C;++c){ float v = xr[c] + bias[c]; xr[c]=v; mu += v; }
  mu /= (float)C;
  float var = 0.f;
  for(int c=0;c<C;++c){ float d = xr[c]-mu; var += d*d; }
  var /= (float)C;
  float inv = rsqrtf(var + 1e-5f);
  for(int c=0;c<C;++c) xr[c] = fmaxf((xr[c]-mu)*inv, 0.f);
}

// ---------------- IGSC ----------------
__global__ void k_copycols(const float* __restrict__ x, float* __restrict__ cat,
                           ll BN, int Cx, int Ctot)
{
  ll i = (ll)blockIdx.x*blockDim.x + threadIdx.x;
  if(i >= BN*(ll)Cx) return;
  int c = (int)(i % Cx); ll r = i / Cx;
  cat[r*(ll)Ctot + c] = x[i];
}
__global__ void k_pos(const float* __restrict__ x, const float* __restrict__ igw,
                      float* __restrict__ cat, float* __restrict__ ds,
                      ll BN, int Cx, int Ctot, int posoff)
{
  ll i = (ll)blockIdx.x*blockDim.x + threadIdx.x;
  if(i>=BN) return;
  const float* xr = x + i*(ll)Cx;
  float p0=0.f,p1=0.f,p2=0.f;
  for(int c=0;c<Cx;++c){
    float v = xr[c];
    p0 += v*igw[c*3+0];
    p1 += v*igw[c*3+1];
    p2 += v*igw[c*3+2];
  }
  float* rowp = cat + i*(ll)Ctot + posoff;
  rowp[0]=p0; rowp[1]=p1; rowp[2]=p2;
  ds[i*3+0]=p0; ds[i*3+1]=p1; ds[i*3+2]=p2;
}
__global__ void k_gsample(const float* __restrict__ feat, float* __restrict__ cat,
                          int B,int N,int Cf,int D,int H,int W,int Ctot,int xoff,int posoff)
{
  ll i = (ll)blockIdx.x*blockDim.x + threadIdx.x;
  ll total = (ll)B*N*Cf;
  if(i>=total) return;
  int c = (int)(i % Cf); ll t = i / Cf;
  int n = (int)(t % N); int b = (int)(t / N);
  float* rowp = cat + ((ll)b*N + n)*Ctot;
  float px = rowp[posoff+0], py = rowp[posoff+1], pz = rowp[posoff+2];
  float gx = (2.f*px - 1.f + 1.f)*0.5f*(W-1);
  float gy = (2.f*py - 1.f + 1.f)*0.5f*(H-1);
  float gz = (2.f*pz - 1.f + 1.f)*0.5f*(D-1);
  float x0 = floorf(gx), y0 = floorf(gy), z0 = floorf(gz);
  const float* fb = feat + ((ll)b*Cf + c)*D*H*W;
  float acc = 0.f;
  for(int dz=0; dz<2; ++dz)
    for(int dy=0; dy<2; ++dy)
      for(int dx=0; dx<2; ++dx){
        float xi = x0+dx, yi = y0+dy, zi = z0+dz;
        float wgt = (1.f-fabsf(gx-xi))*(1.f-fabsf(gy-yi))*(1.f-fabsf(gz-zi));
        bool valid = (xi>=0.f)&&(xi<=(float)(W-1))&&(yi>=0.f)&&(yi<=(float)(H-1))&&(zi>=0.f)&&(zi<=(float)(D-1));
        int xc = min(max((int)xi,0),W-1);
        int yc = min(max((int)yi,0),H-1);
        int zc = min(max((int)zi,0),D-1);
        if(valid) acc += fb[((ll)zc*H + yc)*W + xc]*wgt;
      }
  rowp[xoff + c] = acc;
}

// ---------------- unpool ----------------
__global__ void k_unpool(const float* __restrict__ xin, const int* __restrict__ idx,
                         const float* __restrict__ w, float* __restrict__ out,
                         int B,int Ni,int No,int C)
{
  ll i = (ll)blockIdx.x*blockDim.x + threadIdx.x;
  ll total = (ll)B*No*C;
  if(i>=total) return;
  int c = (int)(i % C); ll t = i / C;
  int no = (int)(t % No); int b = (int)(t / No);
  float s = 0.f;
  for(int k=0;k<3;++k){
    s += xin[((ll)b*Ni + idx[no*3+k])*C + c]*w[no*3+k];
  }
  out[i] = s;
}

// ================= workspace layout (BYTE offsets, total ~126 MiB) =================
static const ll BO_A   = 0;            // f32 scratch; decoder arena
static const ll BO_B   = 75497472;
static const ll BO_C   = 94371840;
static const ll BO_L3  = 103809024;
static const ll BO_L4  = 122683392;
static const ll BO_L5  = 127401984;
static const ll BO_L6  = 129761280;
static const ll BO_P5  = 130940928;
static const ll BO_Z   = 132120576;
// decoder regions inside arena A
static const ll BO_DX   = 0;
static const ll BO_DT1  = 11792000;
static const ll BO_DT2  = 23584000;
static const ll BO_DO   = 35376000;
static const ll BO_DCAT = 41008000;
static const ll BO_DDEG = 46904000;    // float[11000]
static const ll BO_CNT  = 46948096;    // int[11008]
static const ll BO_RP   = 46992128;    // int[11008]  (rowptr, N+1)
static const ll BO_CUR  = 47036160;    // int[11008]
static const ll BO_SRC  = 47080192;    // int[66000]
static const ll BO_CW   = 47344256;    // float[66000]

extern "C" void kernel_launch(void* const* d_in, const int* in_sizes, int n_in,
                              void* d_out, int out_size, void* d_ws, size_t ws_size,
                              hipStream_t stream)
{
  (void)in_sizes; (void)n_in; (void)out_size; (void)ws_size;
  const int B = 4;
  const float* sax = (const float*)d_in[0];
  const float *w1[7], *w2[7], *wsk[7];
  for(int i=1;i<=5;++i){
    w1[i]  = (const float*)d_in[1 + (i-1)*3];
    w2[i]  = (const float*)d_in[2 + (i-1)*3];
    wsk[i] = (const float*)d_in[3 + (i-1)*3];
  }
  w1[6] = (const float*)d_in[16]; w2[6] = (const float*)d_in[17]; wsk[6] = nullptr;
  const float* mu_w = (const float*)d_in[18];
  const float* mu_b = (const float*)d_in[19];
  const float* ld_w = (const float*)d_in[22];
  const float* ld_b = (const float*)d_in[23];
  const float *gcw[5], *gcb[5];
  for(int i=0;i<5;++i){ gcw[i] = (const float*)d_in[24+2*i]; gcb[i] = (const float*)d_in[25+2*i]; }
  const float* gcout_w = (const float*)d_in[34];
  const float* igw[4];
  for(int i=0;i<4;++i) igw[i] = (const float*)d_in[35+i];
  const int* edge[5];
  for(int i=0;i<5;++i) edge[i] = (const int*)d_in[39+i];
  const int* upidx[4]; const float* upw[4];
  for(int i=0;i<4;++i){ upidx[i] = (const int*)d_in[44+2*i]; upw[i] = (const float*)d_in[45+2*i]; }
  float* out = (float*)d_out;
  char* base = (char*)d_ws;

  float* A  = (float*)(base + BO_A);
  float* Bb = (float*)(base + BO_B);
  float* Cb = (float*)(base + BO_C);
  float* L3 = (float*)(base + BO_L3);
  float* L4 = (float*)(base + BO_L4);
  float* L5 = (float*)(base + BO_L5);
  float* L6 = (float*)(base + BO_L6);
  float* P5 = (float*)(base + BO_P5);
  float* Z  = (float*)(base + BO_Z);
  float* DX  = (float*)(base + BO_DX);
  float* DT1 = (float*)(base + BO_DT1);
  float* DT2 = (float*)(base + BO_DT2);
  float* DO_ = (float*)(base + BO_DO);
  float* DCAT= (float*)(base + BO_DCAT);
  float* DDEG= (float*)(base + BO_DDEG);
  int*   CNT = (int*)(base + BO_CNT);
  int*   RP  = (int*)(base + BO_RP);
  int*   CUR = (int*)(base + BO_CUR);
  int*   SRC = (int*)(base + BO_SRC);
  float* CW  = (float*)(base + BO_CW);

  // ============ Encoder ============
  auto convgrid = [&](int DHW, int Co, int COG){ return dim3((unsigned)((DHW+TPB-1)/TPB), Co/COG, B); };

  k_conv1_t<8><<<convgrid(16*192*192,8,8),TPB,0,stream>>>(sax, w1[1], A, 1,8,16,192,192);
  k_conv2respool_t<8><<<convgrid(16*96*96,8,8),TPB,0,stream>>>(A, sax, w2[1], wsk[1], Bb, 8,8,1,16,192,192);
  k_conv1_t<8><<<convgrid(16*96*96,16,8),TPB,0,stream>>>(Bb, w1[2], A, 8,16,16,96,96);
  k_conv2respool_t<8><<<convgrid(16*48*48,16,8),TPB,0,stream>>>(A, Bb, w2[2], wsk[2], Cb, 16,16,8,16,96,96);
  k_conv1_t<8><<<convgrid(16*48*48,32,8),TPB,0,stream>>>(Cb, w1[3], A, 16,32,16,48,48);
  k_conv2res_t<8><<<convgrid(16*48*48,32,8),TPB,0,stream>>>(A, Cb, w2[3], wsk[3], L3, 32,32,16,16,48,48);
  { ll np=(ll)B*32*8*24*24;
    k_maxpool<<<gridFor(np),TPB,0,stream>>>(L3, Bb, B,32,16,48,48,2,2,2); }
  k_conv1_t<8><<<convgrid(8*24*24,64,8),TPB,0,stream>>>(Bb, w1[4], A, 32,64,8,24,24);
  k_conv2res_t<8><<<convgrid(8*24*24,64,8),TPB,0,stream>>>(A, Bb, w2[4], wsk[4], L4, 64,64,32,8,24,24);
  { ll np=(ll)B*64*8*12*12;
    k_maxpool<<<gridFor(np),TPB,0,stream>>>(L4, Cb, B,64,8,24,24,1,2,2); }
  k_conv1_t<8><<<convgrid(8*12*12,128,8),TPB,0,stream>>>(Cb, w1[5], A, 64,128,8,12,12);
  k_conv2res_t<8><<<convgrid(8*12*12,128,8),TPB,0,stream>>>(A, Cb, w2[5], wsk[5], L5, 128,128,64,8,12,12);
  { ll np=(ll)B*128*8*6*6;
    k_maxpool<<<gridFor(np),TPB,0,stream>>>(L5, P5, B,128,8,12,12,1,2,2); }
  k_conv1_t<4><<<convgrid(8*6*6,128,4),TPB,0,stream>>>(P5, w1[6], A, 128,128,8,6,6);
  k_conv2res_t<4><<<convgrid(8*6*6,128,4),TPB,0,stream>>>(A, P5, w2[6], nullptr, L6, 128,128,128,8,6,6);

  k_linear_red<<<dim3(B*64),TPB,0,stream>>>(P5, mu_w, mu_b, Z, 36864, 64);
  k_ld<<<gridFor((ll)B*88064),TPB,0,stream>>>(Z, ld_w, ld_b, DX, B, 88064, 64);

  // ============ Decoder (CSR cheb) ============
  auto build_csr = [&](const int* e, int N, int E){
    const int* row = e; const int* col = e + E;
    k_zero2<<<gridFor(N),TPB,0,stream>>>(DDEG, CNT, N);
    k_degcnt<<<gridFor(E),TPB,0,stream>>>(row, col, DDEG, CNT, E);
    k_scan<<<1,TPB,0,stream>>>(CNT, RP, CUR, N);
    k_fill<<<gridFor(E),TPB,0,stream>>>(row, col, DDEG, CUR, SRC, CW, E);
  };

  auto cheb = [&](float* xin, float* t1, float* t2, float* xout,
                  const int* e, int N, int E, const float* Wg, int Ci, int Co, bool build){
    if(build) build_csr(e, N, E);
    ll BN = (ll)B*N;
    // k = 0
    k_nodemm<<<gridFor(BN*Co),TPB,0,stream>>>(xin, Wg, xout, BN, Ci, Co, 0);
    // k = 1: Tx1 = S(x)
    k_gather<<<gridFor(BN*Ci),TPB,0,stream>>>(xin, nullptr, RP, SRC, CW, t1, B, N, Ci, 0);
    k_nodemm<<<gridFor(BN*Co),TPB,0,stream>>>(t1, Wg+(ll)Ci*Co, xout, BN, Ci, Co, 1);
    float *b0=xin, *b1=t1, *b2=t2;
    for(int k=2;k<6;++k){
      k_gather<<<gridFor(BN*Ci),TPB,0,stream>>>(b1, b0, RP, SRC, CW, b2, B, N, Ci, 1);
      k_nodemm<<<gridFor(BN*Co),TPB,0,stream>>>(b2, Wg+(ll)k*Ci*Co, xout, BN, Ci, Co, 1);
      float* tmp=b0; b0=b1; b1=b2; b2=tmp;
    }
  };

  auto igsc = [&](float* x, float* cat, const float* ig, const float* feat,
                  int N, int Cx, int Cf, int D,int Hh,int Ww, float* ds){
    int Ctot = Cx + Cf + 3;
    ll BN = (ll)B*N;
    k_copycols<<<gridFor(BN*Cx),TPB,0,stream>>>(x, cat, BN, Cx, Ctot);
    k_pos<<<gridFor(BN),TPB,0,stream>>>(x, ig, cat, ds, BN, Cx, Ctot, Cx+Cf);
    k_gsample<<<gridFor(BN*(ll)Cf),TPB,0,stream>>>(feat, cat, B,N,Cf,D,Hh,Ww,Ctot,Cx,Cx+Cf);
  };

  float* out_x  = out;
  float* out_d4 = out + 132000;
  float* out_d3 = out + 198000;
  float* out_d2 = out + 231000;
  float* out_d1 = out + 247500;

  cheb(DX, DT1, DT2, DO_, edge[4], 688, 4128, gcw[0], 128, 64, true);
  k_inorm<<<gridFor((ll)B*688),TPB,0,stream>>>(DO_, gcb[0], (ll)B*688, 64);
  igsc(DO_, DCAT, igw[0], L6, 688, 64, 128, 8,6,6, out_d1);
  k_unpool<<<gridFor((ll)B*1375*195),TPB,0,stream>>>(DCAT, upidx[3], upw[3], DX, B, 688, 1375, 195);

  cheb(DX, DT1, DT2, DO_, edge[3], 1375, 8250, gcw[1], 195, 64, true);
  k_inorm<<<gridFor((ll)B*1375),TPB,0,stream>>>(DO_, gcb[1], (ll)B*1375, 64);
  igsc(DO_, DCAT, igw[1], L5, 1375, 64, 128, 8,12,12, out_d2);
  k_unpool<<<gridFor((ll)B*2750*195),TPB,0,stream>>>(DCAT, upidx[2], upw[2], DX, B, 1375, 2750, 195);

  cheb(DX, DT1, DT2, DO_, edge[2], 2750, 16500, gcw[2], 195, 32, true);
  k_inorm<<<gridFor((ll)B*2750),TPB,0,stream>>>(DO_, gcb[2], (ll)B*2750, 32);
  igsc(DO_, DCAT, igw[2], L4, 2750, 32, 64, 8,24,24, out_d3);
  k_unpool<<<gridFor((ll)B*5500*99),TPB,0,stream>>>(DCAT, upidx[1], upw[1], DX, B, 2750, 5500, 99);

  cheb(DX, DT1, DT2, DO_, edge[1], 5500, 33000, gcw[3], 99, 32, true);
  k_inorm<<<gridFor((ll)B*5500),TPB,0,stream>>>(DO_, gcb[3], (ll)B*5500, 32);
  igsc(DO_, DCAT, igw[3], L3, 5500, 32, 32, 16,48,48, out_d4);
  k_unpool<<<gridFor((ll)B*11000*67),TPB,0,stream>>>(DCAT, upidx[0], upw[0], DX, B, 5500, 11000, 67);

  cheb(DX, DT1, DT2, DO_, edge[0], 11000, 66000, gcw[4], 67, 32, true);
  k_inorm<<<gridFor((ll)B*11000),TPB,0,stream>>>(DO_, gcb[4], (ll)B*11000, 32);

  // GCout reuses edge0's CSR (already built for gc5)
  cheb(DO_, DT1, DT2, DCAT, edge[0], 11000, 66000, gcout_w, 32, 3, false);
  k_copy<<<gridFor(132000LL),TPB,0,stream>>>(DCAT, out_x, 132000LL);
}